// Round 2
// baseline (1253.089 us; speedup 1.0000x reference)
//
#include <hip/hip_runtime.h>

// ---------------------------------------------------------------------------
// LSTM cell, B=8192, D=2048.
//   gates[b][n] = sum_k Acat[b][k] * Wcat[n][k] + bcat[n]
//   Acat = [x | h] bf16 [8192][4096]
//   Wcat row n = 4*d + g : (W_g_x[d][:] | W_g_h[d][:]) bf16, g in {f,i,o,c}
//   bcat[n] = b_g_x[d] + b_g_h[d]
// GEMM: M=8192, N=8192, K=4096, bf16 MFMA 16x16x32, 128x128 tile, BK=32,
// 4 waves (2x2), global_load_lds width-16 staging, fused LSTM epilogue.
// ---------------------------------------------------------------------------

typedef __attribute__((ext_vector_type(8))) short bf16x8;
typedef __attribute__((ext_vector_type(4))) float f32x4;
typedef __attribute__((ext_vector_type(8))) unsigned short u16x8;
typedef unsigned short u16;

static constexpr int D    = 2048;
static constexpr int BATCH= 8192;
static constexpr int KDIM = 2 * D;   // 4096
static constexpr int NDIM = 4 * D;   // 8192
static constexpr int BM = 128, BN = 128, BK = 32;

struct WPtrs {
  const float* wx[4];
  const float* wh[4];
  const float* bx[4];
  const float* bh[4];
};

__device__ __forceinline__ u16 f2bf(float f) {
  unsigned int u = __float_as_uint(f);
  u += 0x7FFFu + ((u >> 16) & 1u);            // round-to-nearest-even
  return (u16)(u >> 16);
}

// ---- pack x,h -> Acat bf16 [BATCH][KDIM] ----------------------------------
__global__ __launch_bounds__(256) void pack_A(const float* __restrict__ x,
                                              const float* __restrict__ h,
                                              u16* __restrict__ A) {
  int tid = blockIdx.x * 256 + threadIdx.x;   // 0 .. BATCH*512-1, 8 elems each
  int row = tid >> 9;
  int k0  = (tid & 511) << 3;
  const float* src = (k0 < D) ? (x + (size_t)row * D + k0)
                              : (h + (size_t)row * D + (k0 - D));
  float4 v0 = *(const float4*)src;
  float4 v1 = *(const float4*)(src + 4);
  u16x8 o;
  o[0] = f2bf(v0.x); o[1] = f2bf(v0.y); o[2] = f2bf(v0.z); o[3] = f2bf(v0.w);
  o[4] = f2bf(v1.x); o[5] = f2bf(v1.y); o[6] = f2bf(v1.z); o[7] = f2bf(v1.w);
  *(u16x8*)(A + (size_t)tid * 8) = o;
}

// ---- pack 8 W + 8 b -> Wcat bf16 [NDIM][KDIM], bcat f32 [NDIM] ------------
__global__ __launch_bounds__(256) void pack_W(WPtrs P, u16* __restrict__ Wc,
                                              float* __restrict__ bc) {
  int tid = blockIdx.x * 256 + threadIdx.x;   // 0 .. NDIM*512-1
  int n  = tid >> 9;
  int kc = tid & 511;
  int k0 = kc << 3;
  int g  = n & 3;       // 0=f 1=i 2=o 3=c
  int d  = n >> 2;
  const float* src = (k0 < D) ? (P.wx[g] + (size_t)d * D + k0)
                              : (P.wh[g] + (size_t)d * D + (k0 - D));
  float4 v0 = *(const float4*)src;
  float4 v1 = *(const float4*)(src + 4);
  u16x8 o;
  o[0] = f2bf(v0.x); o[1] = f2bf(v0.y); o[2] = f2bf(v0.z); o[3] = f2bf(v0.w);
  o[4] = f2bf(v1.x); o[5] = f2bf(v1.y); o[6] = f2bf(v1.z); o[7] = f2bf(v1.w);
  *(u16x8*)(Wc + (size_t)tid * 8) = o;
  if (kc == 0) bc[n] = P.bx[g][d] + P.bh[g][d];
}

// ---- async global->LDS, 16B per lane --------------------------------------
__device__ __forceinline__ void gload_lds16(const u16* g, u16* l) {
  __builtin_amdgcn_global_load_lds(
      (const __attribute__((address_space(1))) unsigned int*)g,
      (__attribute__((address_space(3))) unsigned int*)l, 16, 0, 0);
}

// ---- fused GEMM + LSTM epilogue -------------------------------------------
__global__ __launch_bounds__(256) void lstm_gemm(
    const u16* __restrict__ A, const u16* __restrict__ W,
    const float* __restrict__ bias, const float* __restrict__ cin,
    float* __restrict__ o_out, float* __restrict__ h_out,
    float* __restrict__ c_out) {
  __shared__ u16 As[BM * BK];   // 8 KB
  __shared__ u16 Bs[BN * BK];   // 8 KB

  const int tid  = threadIdx.x;
  const int lane = tid & 63;
  const int wid  = tid >> 6;
  const int wr   = wid >> 1, wc = wid & 1;       // 2x2 waves, 64x64 each
  const int bid  = blockIdx.x;
  const int by   = bid >> 6;                     // 64 M-tiles
  const int bx   = bid & 63;                     // 64 N-tiles
  const int brow = by * BM, bcol = bx * BN;

  f32x4 acc[4][4];
#pragma unroll
  for (int i = 0; i < 4; i++)
#pragma unroll
    for (int j = 0; j < 4; j++) acc[i][j] = (f32x4){0.f, 0.f, 0.f, 0.f};

  // staging: tile = 128 rows x 32 cols bf16 = 8KB = 512 chunks of 16B;
  // chunk c: row = c>>2, k-slot = c&3. LDS byte c*16 = wave_base + lane*16.
  const int c0 = tid, c1 = tid + 256;
  const u16* ga0 = A + (size_t)(brow + (c0 >> 2)) * KDIM + ((c0 & 3) << 3);
  const u16* ga1 = A + (size_t)(brow + (c1 >> 2)) * KDIM + ((c1 & 3) << 3);
  const u16* gb0 = W + (size_t)(bcol + (c0 >> 2)) * KDIM + ((c0 & 3) << 3);
  const u16* gb1 = W + (size_t)(bcol + (c1 >> 2)) * KDIM + ((c1 & 3) << 3);
  u16* lA0 = As + c0 * 8;
  u16* lA1 = As + c1 * 8;
  u16* lB0 = Bs + c0 * 8;
  u16* lB1 = Bs + c1 * 8;

  // fragment LDS element offsets (row = l&15 (+16*f), k = (l>>4)*8)
  const int aoff = (wr * 64 + (lane & 15)) * BK + ((lane >> 4) << 3);
  const int boff = (wc * 64 + (lane & 15)) * BK + ((lane >> 4) << 3);

  for (int kt = 0; kt < KDIM; kt += BK) {
    gload_lds16(ga0, lA0);
    gload_lds16(ga1, lA1);
    gload_lds16(gb0, lB0);
    gload_lds16(gb1, lB1);
    ga0 += BK; ga1 += BK; gb0 += BK; gb1 += BK;
    __syncthreads();    // compiler drains vmcnt before barrier

    bf16x8 af[4], bf[4];
#pragma unroll
    for (int fm = 0; fm < 4; fm++)
      af[fm] = *(const bf16x8*)(As + aoff + fm * 16 * BK);
#pragma unroll
    for (int fn = 0; fn < 4; fn++)
      bf[fn] = *(const bf16x8*)(Bs + boff + fn * 16 * BK);
#pragma unroll
    for (int fm = 0; fm < 4; fm++)
#pragma unroll
      for (int fn = 0; fn < 4; fn++)
        acc[fm][fn] = __builtin_amdgcn_mfma_f32_16x16x32_bf16(
            af[fm], bf[fn], acc[fm][fn], 0, 0, 0);
    __syncthreads();
  }

  // ---- fused LSTM epilogue ----
  // C-frag: col = lane&15, row = (lane>>4)*4 + r  [HW-verified layout]
  // col n -> gate g = n&3, d = n>>2 ; 4 gates live in lanes differing in low
  // 2 bits -> gather with shfl_xor(1)/shfl_xor(2).
  const int colg = lane & 15;
  const int g    = colg & 3;
  const int rb   = brow + wr * 64 + ((lane >> 4) << 2);
#pragma unroll
  for (int fm = 0; fm < 4; fm++) {
#pragma unroll
    for (int fn = 0; fn < 4; fn++) {
      const int   ncol = bcol + wc * 64 + fn * 16 + colg;
      const float bv   = bias[ncol];
      const int   d    = ncol >> 2;
#pragma unroll
      for (int r = 0; r < 4; r++) {
        const int grow = rb + fm * 16 + r;
        float v  = acc[fm][fn][r] + bv;
        float p  = __shfl_xor(v, 1);
        float e0 = (g & 1) ? p : v;    // gate (g & ~1)
        float o1 = (g & 1) ? v : p;    // gate (g | 1)
        float q0 = __shfl_xor(e0, 2);
        float q1 = __shfl_xor(o1, 2);
        float gf = (g & 2) ? q0 : e0;  // gate 0 = f
        float gi = (g & 2) ? q1 : o1;  // gate 1 = i
        float go = (g & 2) ? e0 : q0;  // gate 2 = o
        float gc = (g & 2) ? o1 : q1;  // gate 3 = c~
        float fv = 1.f / (1.f + __expf(-gf));
        float iv = 1.f / (1.f + __expf(-gi));
        float ov = 1.f / (1.f + __expf(-go));
        float tv = 2.f / (1.f + __expf(-2.f * gc)) - 1.f;
        size_t idx = (size_t)grow * D + d;
        float cv = cin[idx];
        float cn = fv * cv + iv * tv;
        float hn = ov * cn;
        if (g == 0)      o_out[idx] = ov;
        else if (g == 1) h_out[idx] = hn;
        else if (g == 2) c_out[idx] = cn;
      }
    }
  }
}

// ---------------------------------------------------------------------------
extern "C" void kernel_launch(void* const* d_in, const int* in_sizes, int n_in,
                              void* d_out, int out_size, void* d_ws,
                              size_t ws_size, hipStream_t stream) {
  const float* x = (const float*)d_in[0];
  const float* h = (const float*)d_in[1];
  const float* c = (const float*)d_in[2];

  WPtrs wp;
  // input order: W_f_x,b_f_x,W_f_h,b_f_h, W_i_x,... gate order f,i,o,c
#pragma unroll
  for (int g = 0; g < 4; g++) {
    wp.wx[g] = (const float*)d_in[3 + 4 * g];
    wp.bx[g] = (const float*)d_in[4 + 4 * g];
    wp.wh[g] = (const float*)d_in[5 + 4 * g];
    wp.bh[g] = (const float*)d_in[6 + 4 * g];
  }

  u16*   A_cat = (u16*)d_ws;                                   // 64 MB
  u16*   W_cat = (u16*)((char*)d_ws + (size_t)67108864);       // 64 MB
  float* b_cat = (float*)((char*)d_ws + (size_t)134217728);    // 32 KB

  pack_A<<<(BATCH * 512) / 256, 256, 0, stream>>>(x, h, A_cat);
  pack_W<<<(NDIM * 512) / 256, 256, 0, stream>>>(wp, W_cat, b_cat);

  float* o_out = (float*)d_out;
  float* h_out = o_out + (size_t)BATCH * D;
  float* c_out = h_out + (size_t)BATCH * D;

  lstm_gemm<<<(BATCH / BM) * (NDIM / BN), 256, 0, stream>>>(
      A_cat, W_cat, b_cat, c, o_out, h_out, c_out);
}